// Round 4
// baseline (596.153 us; speedup 1.0000x reference)
//
#include <hip/hip_runtime.h>

#define F    128
#define FQ   32    // F/4 (float4 per row)
#define FU   64    // uints per bf16 row
#define RPB  128   // rows per bucket
#define BSH  7     // log2(RPB)
#define TILE 2048  // edges per histogram tile (256 thr x 8)
#define SCAP 4096  // max edges per bucket section (mean 2046, +45 sigma)
#define LSTR 68    // LDS row stride in dwords (136 bf16): 16-B aligned, 2-way banks
#define PCAP 2048  // staged pairs per 64-row spmm block (mean 1024, +32 sigma)

typedef __attribute__((ext_vector_type(8))) short short8;   // MFMA A/B frag (8 bf16)
typedef __attribute__((ext_vector_type(4))) float f32x4;    // MFMA C/D frag
typedef __attribute__((ext_vector_type(4))) unsigned int u32x4;

// pack two fp32 -> two bf16 (RNE) in one uint (a = low = even feature)
__device__ __forceinline__ unsigned int f2bf2(float a, float b) {
    unsigned int ua = __float_as_uint(a);
    unsigned int ub = __float_as_uint(b);
    ua = (ua + 0x7fffu + ((ua >> 16) & 1u)) >> 16;
    ub = (ub + 0x7fffu + ((ub >> 16) & 1u)) >> 16;
    return ua | (ub << 16);
}
__device__ __forceinline__ unsigned short f2bf1(float a) {
    unsigned int ua = __float_as_uint(a);
    return (unsigned short)((ua + 0x7fffu + ((ua >> 16) & 1u)) >> 16);
}

__device__ __forceinline__ void fma8(float* acc, uint4 g, float wt) {
    unsigned int uu[4] = {g.x, g.y, g.z, g.w};
    #pragma unroll
    for (int j = 0; j < 4; ++j) {
        acc[2 * j]     = fmaf(wt, __uint_as_float(uu[j] << 16), acc[2 * j]);
        acc[2 * j + 1] = fmaf(wt, __uint_as_float(uu[j] & 0xffff0000u), acc[2 * j + 1]);
    }
}

// pairs read: LDS-staged fast path, global NT fallback for (rare) overflow.
// Invalid slots are clamped into the staged range and masked to col=0/wt=0.
__device__ __forceinline__ void ldpair_lds(const long long* __restrict__ ep,
                                           const int2* __restrict__ gp,
                                           int s0, int sLen, int sLen1,
                                           int e, bool valid, int& c, float& w) {
    int idx = e - s0;
    long long v;
    if (valid && idx >= sLen) {      // true overflow: block range > PCAP (~never)
        v = __builtin_nontemporal_load((const long long*)(gp + e));
    } else {
        v = ep[min(idx, sLen1 - 1)];
    }
    unsigned long long u = (unsigned long long)v;
    c = valid ? (int)(unsigned int)(u & 0xffffffffull) : 0;
    w = valid ? __uint_as_float((unsigned int)(u >> 32)) : 0.f;
}

// ---------------------------------------------------------------------------
// MFMA GEMM: H = In @ W -> packed bf16 in XCD-SLICED layout:
//   H_sliced[s][n][16 feats], s = feat >> 4   (slice strip = 32 B per node)
// BN=false: X is fp32 [N][128].  BN=true: X is sliced packed bf16, transformed
// relu(a[k]*x+c[k]) at staging, with a,c computed per-thread from stats
// (bnfinal kernel folded in here: one fewer graph node).
// ---------------------------------------------------------------------------
template <bool BN>
__global__ __launch_bounds__(256) void gemm_kernel(const void* __restrict__ Xv,
                                                   const float* __restrict__ W,
                                                   const float* __restrict__ stats,
                                                   const float* __restrict__ gamma,
                                                   const float* __restrict__ beta,
                                                   float invN,
                                                   unsigned int* __restrict__ Hb,
                                                   int nNodes) {
    __shared__ unsigned int XtU[64 * LSTR];    // bf16 pairs: Xt[node][k]
    __shared__ unsigned int WtU[128 * LSTR];   // bf16 pairs: Wt[feat][k]

    const int tid = threadIdx.x;
    const int bn0 = blockIdx.x * 64;

    // ---- stage W transposed ----
    {
        int f = tid >> 1;
        int kh = (tid & 1) * 64;
        #pragma unroll
        for (int k8 = 0; k8 < 8; ++k8) {
            int k0 = kh + k8 * 8;
            float v[8];
            #pragma unroll
            for (int i = 0; i < 8; ++i) v[i] = W[(size_t)(k0 + i) * F + f];
            uint4 pk;
            pk.x = f2bf2(v[0], v[1]);
            pk.y = f2bf2(v[2], v[3]);
            pk.z = f2bf2(v[4], v[5]);
            pk.w = f2bf2(v[6], v[7]);
            *(uint4*)&WtU[f * LSTR + k0 / 2] = pk;
        }
    }
    // ---- stage X tile as bf16, optional BN+ReLU (BN coeffs computed here) ----
    {
        const int kqc = tid & 31;              // (tid + it*256) & 31 is constant
        float4 a4, c4;
        if (BN) {
            float4 s  = ((const float4*)stats)[kqc];
            float4 sq = ((const float4*)(stats + 128))[kqc];
            float4 g4 = ((const float4*)gamma)[kqc];
            float4 b4 = ((const float4*)beta)[kqc];
            float m;
            m = s.x * invN; a4.x = g4.x * rsqrtf(sq.x * invN - m * m + 1e-5f); c4.x = b4.x - m * a4.x;
            m = s.y * invN; a4.y = g4.y * rsqrtf(sq.y * invN - m * m + 1e-5f); c4.y = b4.y - m * a4.y;
            m = s.z * invN; a4.z = g4.z * rsqrtf(sq.z * invN - m * m + 1e-5f); c4.z = b4.z - m * a4.z;
            m = s.w * invN; a4.w = g4.w * rsqrtf(sq.w * invN - m * m + 1e-5f); c4.w = b4.w - m * a4.w;
        }
        #pragma unroll
        for (int it = 0; it < 8; ++it) {
            int i = tid + it * 256;            // 0..2047
            int n = i >> 5;                    // node 0..63
            int node = bn0 + n;
            uint2 pk = make_uint2(0u, 0u);
            if (BN) {
                // sliced bf16 input: slice = kqc>>2, uint2 idx (kqc&3) in strip
                uint2 raw = make_uint2(0u, 0u);
                if (node < nNodes)
                    raw = ((const uint2*)Xv)[((size_t)(kqc >> 2) * nNodes + node) * 4 + (kqc & 3)];
                float4 v;
                v.x = __uint_as_float(raw.x << 16);
                v.y = __uint_as_float(raw.x & 0xffff0000u);
                v.z = __uint_as_float(raw.y << 16);
                v.w = __uint_as_float(raw.y & 0xffff0000u);
                v.x = fmaxf(fmaf(a4.x, v.x, c4.x), 0.f);
                v.y = fmaxf(fmaf(a4.y, v.y, c4.y), 0.f);
                v.z = fmaxf(fmaf(a4.z, v.z, c4.z), 0.f);
                v.w = fmaxf(fmaf(a4.w, v.w, c4.w), 0.f);
                pk = make_uint2(f2bf2(v.x, v.y), f2bf2(v.z, v.w));
            } else {
                float4 v = make_float4(0.f, 0.f, 0.f, 0.f);
                if (node < nNodes) v = ((const float4*)Xv)[(size_t)node * FQ + kqc];
                pk = make_uint2(f2bf2(v.x, v.y), f2bf2(v.z, v.w));
            }
            *(uint2*)&XtU[n * LSTR + kqc * 2] = pk;
        }
    }
    __syncthreads();

    // ---- MFMA compute ----
    const int l = tid & 63;
    const int wv = tid >> 6;
    const int quad = l >> 4, lo = l & 15;
    const int fb = wv * 32;

    f32x4 acc[4][2];
    #pragma unroll
    for (int nt = 0; nt < 4; ++nt)
        #pragma unroll
        for (int ft = 0; ft < 2; ++ft) acc[nt][ft] = (f32x4){0.f, 0.f, 0.f, 0.f};

    #pragma unroll
    for (int kc = 0; kc < 4; ++kc) {
        int koff = kc * 16 + quad * 4;
        short8 a[4], b[2];
        #pragma unroll
        for (int nt = 0; nt < 4; ++nt)
            a[nt] = *(const short8*)&XtU[(nt * 16 + lo) * LSTR + koff];
        #pragma unroll
        for (int ft = 0; ft < 2; ++ft)
            b[ft] = *(const short8*)&WtU[(fb + ft * 16 + lo) * LSTR + koff];
        #pragma unroll
        for (int nt = 0; nt < 4; ++nt)
            #pragma unroll
            for (int ft = 0; ft < 2; ++ft)
                acc[nt][ft] = __builtin_amdgcn_mfma_f32_16x16x32_bf16(
                    a[nt], b[ft], acc[nt][ft], 0, 0, 0);
    }

    // ---- epilogue: bf16 store into SLICED layout (slice = wv*2+ft) ----
    unsigned short* Hs = (unsigned short*)Hb;
    #pragma unroll
    for (int nt = 0; nt < 4; ++nt) {
        #pragma unroll
        for (int reg = 0; reg < 4; ++reg) {
            int node = bn0 + nt * 16 + quad * 4 + reg;
            if (node < nNodes) {
                #pragma unroll
                for (int ft = 0; ft < 2; ++ft)
                    Hs[((size_t)(wv * 2 + ft) * nNodes + node) * 16 + lo] =
                        f2bf1(acc[nt][ft][reg]);
            }
        }
    }
}

// ---------------------------------------------------------------------------
// CSR build via deterministic bucket sort — NO returning global atomics.
// ---------------------------------------------------------------------------
__global__ __launch_bounds__(256) void histo_kernel(const int* __restrict__ row,
                                                    int* __restrict__ hist,
                                                    int NB, int E) {
    __shared__ int h[1024];
    int t = threadIdx.x;
    for (int i = t; i < NB; i += 256) h[i] = 0;
    __syncthreads();
    int base = blockIdx.x * TILE + t * 8;
    if (base + 7 < E) {
        int4 a = ((const int4*)row)[(base >> 2) + 0];
        int4 b = ((const int4*)row)[(base >> 2) + 1];
        atomicAdd(&h[a.x >> BSH], 1); atomicAdd(&h[a.y >> BSH], 1);
        atomicAdd(&h[a.z >> BSH], 1); atomicAdd(&h[a.w >> BSH], 1);
        atomicAdd(&h[b.x >> BSH], 1); atomicAdd(&h[b.y >> BSH], 1);
        atomicAdd(&h[b.z >> BSH], 1); atomicAdd(&h[b.w >> BSH], 1);
    } else {
        for (int j = 0; j < 8; ++j)
            if (base + j < E) atomicAdd(&h[row[base + j] >> BSH], 1);
    }
    __syncthreads();
    for (int i = t; i < NB; i += 256) hist[(size_t)blockIdx.x * NB + i] = h[i];
}

__global__ __launch_bounds__(256) void btot_kernel(const int* __restrict__ hist,
                                                   int* __restrict__ total,
                                                   int nT, int NB) {
    int b = blockIdx.x;
    int s = 0;
    for (int t = threadIdx.x; t < nT; t += 256) s += hist[(size_t)t * NB + b];
    __shared__ int red[256];
    red[threadIdx.x] = s;
    __syncthreads();
    for (int o = 128; o > 0; o >>= 1) {
        if (threadIdx.x < o) red[threadIdx.x] += red[threadIdx.x + o];
        __syncthreads();
    }
    if (threadIdx.x == 0) total[b] = red[0];
}

__global__ __launch_bounds__(1024) void bstart_kernel(const int* __restrict__ total,
                                                      int* __restrict__ start,
                                                      int NB, int E) {
    __shared__ int sh[1024];
    int t = threadIdx.x;
    int v = (t < NB) ? total[t] : 0;
    sh[t] = v;
    __syncthreads();
    #pragma unroll
    for (int o = 1; o < 1024; o <<= 1) {
        int add = (t >= o) ? sh[t - o] : 0;
        __syncthreads();
        sh[t] += add;
        __syncthreads();
    }
    if (t < NB) start[t] = sh[t] - v;
    if (t == 0) start[NB] = E;
}

__global__ __launch_bounds__(1024) void boff_kernel(const int* __restrict__ hist,
                                                    const int* __restrict__ start,
                                                    int* __restrict__ off,
                                                    int nT, int NB) {
    __shared__ int sh[1024];
    int b = blockIdx.x, t = threadIdx.x;
    int v = (t < nT) ? hist[(size_t)t * NB + b] : 0;
    sh[t] = v;
    __syncthreads();
    #pragma unroll
    for (int o = 1; o < 1024; o <<= 1) {
        int add = (t >= o) ? sh[t - o] : 0;
        __syncthreads();
        sh[t] += add;
        __syncthreads();
    }
    if (t < nT) off[(size_t)b * nT + t] = start[b] + sh[t] - v;
}

__global__ __launch_bounds__(256) void bplace_kernel(const int* __restrict__ row,
                                                     const int* __restrict__ col,
                                                     const float* __restrict__ w,
                                                     const int* __restrict__ off,
                                                     int2* __restrict__ tmp,
                                                     int nT, int NB, int E) {
    __shared__ int h[1024];
    int t = threadIdx.x, tile = blockIdx.x;
    for (int i = t; i < NB; i += 256) h[i] = 0;
    __syncthreads();
    int base = tile * TILE + t * 8;
    int r[8], c[8];
    float ww[8];
    int nv = 0;
    if (base + 7 < E) {
        int4 ra = ((const int4*)row)[(base >> 2) + 0];
        int4 rb = ((const int4*)row)[(base >> 2) + 1];
        int4 ca = ((const int4*)col)[(base >> 2) + 0];
        int4 cb = ((const int4*)col)[(base >> 2) + 1];
        float4 wa = ((const float4*)w)[(base >> 2) + 0];
        float4 wb = ((const float4*)w)[(base >> 2) + 1];
        r[0] = ra.x; r[1] = ra.y; r[2] = ra.z; r[3] = ra.w;
        r[4] = rb.x; r[5] = rb.y; r[6] = rb.z; r[7] = rb.w;
        c[0] = ca.x; c[1] = ca.y; c[2] = ca.z; c[3] = ca.w;
        c[4] = cb.x; c[5] = cb.y; c[6] = cb.z; c[7] = cb.w;
        ww[0] = wa.x; ww[1] = wa.y; ww[2] = wa.z; ww[3] = wa.w;
        ww[4] = wb.x; ww[5] = wb.y; ww[6] = wb.z; ww[7] = wb.w;
        nv = 8;
    } else {
        for (int j = 0; j < 8; ++j)
            if (base + j < E) { r[nv] = row[base + j]; c[nv] = col[base + j];
                                ww[nv] = w[base + j]; ++nv; }
    }
    #pragma unroll 8
    for (int j = 0; j < 8; ++j) {
        if (j >= nv) break;
        int b = r[j] >> BSH;
        int rank = atomicAdd(&h[b], 1);
        int pos = off[(size_t)b * nT + tile] + rank;
        tmp[pos] = make_int2(((r[j] & (RPB - 1)) << 25) | c[j], __float_as_int(ww[j]));
    }
}

__global__ __launch_bounds__(256) void bsort_kernel(const int2* __restrict__ tmp,
                                                    const int* __restrict__ start,
                                                    int2* __restrict__ pairs,
                                                    int* __restrict__ rowptr,
                                                    int N, int NB, int E) {
    __shared__ int cntB[RPB];
    __shared__ int cntS[RPB];
    __shared__ int sc[RPB];
    __shared__ int2 outP[SCAP];
    int b = blockIdx.x, t = threadIdx.x;
    int s0 = start[b], s1 = start[b + 1];
    int len = s1 - s0;
    if (len > SCAP) len = SCAP;

    if (t < RPB) cntB[t] = 0;
    __syncthreads();

    int2 p[16];
    int np = 0;
    #pragma unroll
    for (int k = 0; k < 16; ++k) {
        int i = t + k * 256;
        if (i < len) { p[k] = tmp[s0 + i]; ++np; }
    }
    #pragma unroll
    for (int k = 0; k < 16; ++k) {
        if (k >= np) break;
        atomicAdd(&cntB[((unsigned)p[k].x) >> 25], 1);
    }
    __syncthreads();
    int val = (t < RPB) ? cntB[t] : 0;
    if (t < RPB) sc[t] = val;
    __syncthreads();
    #pragma unroll
    for (int o = 1; o < RPB; o <<= 1) {
        int add = (t < RPB && t >= o) ? sc[t - o] : 0;
        __syncthreads();
        if (t < RPB) sc[t] += add;
        __syncthreads();
    }
    if (t < RPB) { int ex = sc[t] - val; cntB[t] = ex; cntS[t] = ex; }
    __syncthreads();
    #pragma unroll
    for (int k = 0; k < 16; ++k) {
        if (k >= np) break;
        int rl = ((unsigned)p[k].x) >> 25;
        int lr = atomicAdd(&cntB[rl], 1);
        outP[lr] = make_int2(p[k].x & 0x1ffffff, p[k].y);
    }
    __syncthreads();
    for (int i = t; i < len; i += 256) pairs[s0 + i] = outP[i];
    int r0 = b * RPB;
    if (t < RPB && r0 + t < N) rowptr[r0 + t] = s0 + cntS[t];
    if (b == NB - 1 && t == 0) rowptr[N] = E;
}

// ---------------------------------------------------------------------------
// XCD-SLICED CSR SpMM v4.  slice = blockIdx.x & 7 pins a 16-feat strip
// (N*32B = 3.2 MB < 4 MiB per-XCD L2) to one XCD; gathers are L2 hits.
// Round-3 post-mortem: still latency-bound (VALUBusy 33%) — the NT pairs
// load (HBM, no L2 allocate, ~900cy) sat on the critical path of every
// iteration.  v4: a 64-row block's edges are one CONTIGUOUS pairs range
// (CSR!), staged into LDS once per block with coalesced NT loads.  The
// per-iteration chain is then ds_read(~120cy) -> L2-hit gather, MLP 4.
// All outputs are NT stores so the streaming writes don't evict the hot
// H slice from L2.  Wave = 2 rows x 16 slots x 2 halves (uint4/lane).
// ---------------------------------------------------------------------------
template <bool BF16OUT>
__global__ __launch_bounds__(256) void spmm_sl_kernel(const int* __restrict__ rowptr,
                                                      const int2* __restrict__ pairs,
                                                      const unsigned int* __restrict__ Hsl,
                                                      const float* __restrict__ bias,
                                                      void* __restrict__ outv,
                                                      int N, int E) {
    const int slice = blockIdx.x & 7;          // -> XCD (bid % 8 round-robin)
    const int rb    = blockIdx.x >> 3;
    const int r0    = rb * 64;
    const int l     = threadIdx.x & 63;
    const int wv    = threadIdx.x >> 6;
    const int rsub  = l >> 5;                  // row within pair (0..1)
    const int slot  = (l >> 1) & 15;           // edge slot (0..15)
    const int half  = l & 1;                   // 8-feat half of the strip

    __shared__ int rp[65];
    __shared__ long long ep[PCAP];

    if (threadIdx.x < 65) {
        int rr = r0 + threadIdx.x;
        rp[threadIdx.x] = rowptr[min(rr, N)];
    }
    // block's edge range is contiguous: stage it into LDS (coalesced NT)
    const int s0   = rowptr[r0];
    const int sEnd = rowptr[min(r0 + 64, N)];
    const int sLen = min(sEnd - s0, PCAP);
    const int sLen1 = max(sLen, 1);
    for (int i = threadIdx.x; i < sLen; i += 256)
        ep[i] = __builtin_nontemporal_load((const long long*)(pairs + s0 + i));

    float4 bs0 = make_float4(0.f, 0.f, 0.f, 0.f), bs1 = bs0;
    if (!BF16OUT && bias) {
        const int fb = slice * 16 + half * 8;
        bs0 = ((const float4*)bias)[fb >> 2];
        bs1 = ((const float4*)bias)[(fb >> 2) + 1];
    }
    __syncthreads();

    const uint4* H4 = (const uint4*)Hsl + (size_t)slice * N * 2;

    #pragma unroll 1
    for (int it = 0; it < 8; it += 2) {
        const int lrA = wv * 16 + it * 2 + rsub;     // local rows A, B = A+2
        const int iA0 = rp[lrA],     iA1 = rp[lrA + 1];
        const int iB0 = rp[lrA + 2], iB1 = rp[lrA + 3];

        const int eA = iA0 + slot, eB = iB0 + slot;
        const bool vA0 = eA < iA1,      vA1 = eA + 16 < iA1;
        const bool vB0 = eB < iB1,      vB1 = eB + 16 < iB1;

        // 4 independent pairs reads from LDS (global NT only on overflow)
        int cA0, cA1, cB0, cB1;
        float wA0, wA1, wB0, wB1;
        ldpair_lds(ep, pairs, s0, sLen, sLen1, eA,      vA0, cA0, wA0);
        ldpair_lds(ep, pairs, s0, sLen, sLen1, eA + 16, vA1, cA1, wA1);
        ldpair_lds(ep, pairs, s0, sLen, sLen1, eB,      vB0, cB0, wB0);
        ldpair_lds(ep, pairs, s0, sLen, sLen1, eB + 16, vB1, cB1, wB1);

        // 4 independent gathers (L2-resident slice)
        uint4 gA0 = H4[(size_t)cA0 * 2 + half];
        uint4 gA1 = H4[(size_t)cA1 * 2 + half];
        uint4 gB0 = H4[(size_t)cB0 * 2 + half];
        uint4 gB1 = H4[(size_t)cB1 * 2 + half];

        float accA[8], accB[8];
        #pragma unroll
        for (int j = 0; j < 8; ++j) { accA[j] = 0.f; accB[j] = 0.f; }
        fma8(accA, gA0, wA0); fma8(accA, gA1, wA1);
        fma8(accB, gB0, wB0); fma8(accB, gB1, wB1);

        // rare tails: deg > 32 (P ~ 2e-4 per row)
        for (int e = iA0 + 32 + slot; e < iA1; e += 16) {
            int c; float w;
            ldpair_lds(ep, pairs, s0, sLen, sLen1, e, true, c, w);
            uint4 g = H4[(size_t)c * 2 + half];
            fma8(accA, g, w);
        }
        for (int e = iB0 + 32 + slot; e < iB1; e += 16) {
            int c; float w;
            ldpair_lds(ep, pairs, s0, sLen, sLen1, e, true, c, w);
            uint4 g = H4[(size_t)c * 2 + half];
            fma8(accB, g, w);
        }

        // reduce over the 16 edge slots (lane bits 1..4)
        #pragma unroll
        for (int j = 0; j < 8; ++j) {
            accA[j] += __shfl_xor(accA[j], 2, 64);
            accA[j] += __shfl_xor(accA[j], 4, 64);
            accA[j] += __shfl_xor(accA[j], 8, 64);
            accA[j] += __shfl_xor(accA[j], 16, 64);
            accB[j] += __shfl_xor(accB[j], 2, 64);
            accB[j] += __shfl_xor(accB[j], 4, 64);
            accB[j] += __shfl_xor(accB[j], 8, 64);
            accB[j] += __shfl_xor(accB[j], 16, 64);
        }

        if (slot == 0) {
            const int rA = r0 + lrA;
            #pragma unroll
            for (int sel = 0; sel < 2; ++sel) {
                const int r = rA + sel * 2;
                const float* acc = sel ? accB : accA;
                if (r < N) {
                    if (BF16OUT) {
                        u32x4 pk;
                        pk.x = f2bf2(acc[0], acc[1]);
                        pk.y = f2bf2(acc[2], acc[3]);
                        pk.z = f2bf2(acc[4], acc[5]);
                        pk.w = f2bf2(acc[6], acc[7]);
                        u32x4* O = (u32x4*)outv;
                        __builtin_nontemporal_store(pk, &O[((size_t)slice * N + r) * 2 + half]);
                    } else {
                        f32x4 v0 = (f32x4){acc[0] + bs0.x, acc[1] + bs0.y,
                                           acc[2] + bs0.z, acc[3] + bs0.w};
                        f32x4 v1 = (f32x4){acc[4] + bs1.x, acc[5] + bs1.y,
                                           acc[6] + bs1.z, acc[7] + bs1.w};
                        f32x4* O = (f32x4*)outv;
                        const int fb = slice * 16 + half * 8;
                        __builtin_nontemporal_store(v0, &O[(size_t)r * 32 + (fb >> 2)]);
                        __builtin_nontemporal_store(v1, &O[(size_t)r * 32 + (fb >> 2) + 1]);
                    }
                }
            }
        }
    }
}

// ---------------------------------------------------------------------------
// BN batch statistics over SLICED packed-bf16 input: per-feature sum/sumsq.
// ---------------------------------------------------------------------------
__global__ __launch_bounds__(256) void bnstats_kernel(const unsigned int* __restrict__ Hu,
                                                      float* __restrict__ sums,
                                                      int nNodes) {
    int u = threadIdx.x & 63;   // uint slot: slice u>>3, offset u&7
    int g = threadIdx.x >> 6;   // 0..3
    const unsigned int* base = Hu + (size_t)(u >> 3) * nNodes * 8 + (u & 7);
    int stride = gridDim.x * 4;
    float s0 = 0.f, s1 = 0.f, q0 = 0.f, q1 = 0.f;
    for (int n = blockIdx.x * 4 + g; n < nNodes; n += stride) {
        unsigned int v = base[(size_t)n * 8];
        float a = __uint_as_float(v << 16);
        float b = __uint_as_float(v & 0xffff0000u);
        s0 += a; s1 += b;
        q0 = fmaf(a, a, q0); q1 = fmaf(b, b, q1);
    }
    __shared__ float4 red[256];
    red[threadIdx.x] = make_float4(s0, s1, q0, q1);
    __syncthreads();
    if (g == 0) {
        float4 r0 = red[u], r1 = red[64 + u], r2 = red[128 + u], r3 = red[192 + u];
        int f0 = (u >> 3) * 16 + (u & 7) * 2;
        atomicAdd(&sums[f0],           r0.x + r1.x + r2.x + r3.x);
        atomicAdd(&sums[f0 + 1],       r0.y + r1.y + r2.y + r3.y);
        atomicAdd(&sums[128 + f0],     r0.z + r1.z + r2.z + r3.z);
        atomicAdd(&sums[128 + f0 + 1], r0.w + r1.w + r2.w + r3.w);
    }
}

extern "C" void kernel_launch(void* const* d_in, const int* in_sizes, int n_in,
                              void* d_out, int out_size, void* d_ws, size_t ws_size,
                              hipStream_t stream) {
    const float* x    = (const float*)d_in[0];
    const int*   erow = (const int*)d_in[1];
    const int*   ecol = (const int*)d_in[2];
    const float* ew   = (const float*)d_in[3];
    const float* W1   = (const float*)d_in[4];
    // d_in[5] = b1: unused — cancels exactly under BatchNorm mean subtraction.
    const float* W2   = (const float*)d_in[6];
    const float* b2   = (const float*)d_in[7];
    const float* gmm  = (const float*)d_in[8];
    const float* beta = (const float*)d_in[9];
    float* out = (float*)d_out;

    const int N = in_sizes[0] / F;   // 100000
    const int E = in_sizes[1];       // 1600000

    const int NB = (N + RPB - 1) / RPB;     // 782
    const int nT = (E + TILE - 1) / TILE;   // 782

    // ---- workspace carve-up ----
    unsigned int* buf1   = (unsigned int*)d_ws;                   // N*FU bf16 (h1, sliced)
    unsigned int* Hb     = buf1 + (size_t)N * FU;                 // N*FU bf16 (h0/h2, sliced)
    float*        stats  = (float*)(Hb + (size_t)N * FU);         // 256
    int*          rowptr = (int*)(stats + 256);                   // N+2
    int*          start  = rowptr + N + 2;                        // 1028
    int*          total  = start + 1028;                          // 1024
    int*          hist   = total + 1024;                          // nT*NB
    int*          off    = hist + (size_t)nT * NB;                // NB*nT
    int2*         tmp    = (int2*)(off + (size_t)NB * nT);        // E
    int2*         pairs  = tmp + E;                               // E

    const int gemmGrid = (N + 63) / 64;
    const int spmmGrid = ((N + 63) / 64) * 8;   // 64-row blocks x 8 slices

    hipMemsetAsync(stats, 0, 256 * sizeof(float), stream);

    // ---- build CSR: deterministic bucket sort, shared by both layers ----
    histo_kernel<<<nT, 256, 0, stream>>>(erow, hist, NB, E);
    btot_kernel<<<NB, 256, 0, stream>>>(hist, total, nT, NB);
    bstart_kernel<<<1, 1024, 0, stream>>>(total, start, NB, E);
    boff_kernel<<<NB, 1024, 0, stream>>>(hist, start, off, nT, NB);
    bplace_kernel<<<nT, 256, 0, stream>>>(erow, ecol, ew, off, tmp, nT, NB, E);
    bsort_kernel<<<NB, 256, 0, stream>>>(tmp, start, pairs, rowptr, N, NB, E);

    // Layer 1: Hb = bf16(x @ W1) sliced ; buf1 = bf16(A @ Hb) sliced
    gemm_kernel<false><<<gemmGrid, 256, 0, stream>>>(x, W1, nullptr, nullptr,
                                                     nullptr, 0.f, Hb, N);
    spmm_sl_kernel<true><<<spmmGrid, 256, 0, stream>>>(rowptr, pairs, Hb,
                                                       nullptr, buf1, N, E);
    // BN stats (fold happens inside gemm<true>)
    bnstats_kernel<<<400, 256, 0, stream>>>(buf1, stats, N);
    // Layer 2: Hb = bf16(relu(bn(buf1)) @ W2) sliced ; out = A @ Hb + b2 (fp32)
    gemm_kernel<true><<<gemmGrid, 256, 0, stream>>>(buf1, W2, stats, gmm, beta,
                                                    1.0f / (float)N, Hb, N);
    spmm_sl_kernel<false><<<spmmGrid, 256, 0, stream>>>(rowptr, pairs, Hb,
                                                        b2, out, N, E);
}

// Round 5
// 413.162 us; speedup vs baseline: 1.4429x; 1.4429x over previous
//
#include <hip/hip_runtime.h>

#define F    128
#define FQ   32    // F/4 (float4 per row)
#define FU   64    // uints per bf16 row
#define RPB  128   // rows per bucket
#define BSH  7     // log2(RPB)
#define TILE 2048  // edges per histogram tile (256 thr x 8)
#define SCAP 4096  // max edges per bucket section (mean 2046, +45 sigma)
#define LSTR 68    // LDS row stride in dwords (136 bf16): 16-B aligned, 2-way banks

typedef __attribute__((ext_vector_type(8))) short short8;   // MFMA A/B frag (8 bf16)
typedef __attribute__((ext_vector_type(4))) float f32x4;    // MFMA C/D frag
typedef __attribute__((ext_vector_type(4))) unsigned int u32x4;

// pack two fp32 -> two bf16 (RNE) in one uint (a = low = even feature)
__device__ __forceinline__ unsigned int f2bf2(float a, float b) {
    unsigned int ua = __float_as_uint(a);
    unsigned int ub = __float_as_uint(b);
    ua = (ua + 0x7fffu + ((ua >> 16) & 1u)) >> 16;
    ub = (ub + 0x7fffu + ((ub >> 16) & 1u)) >> 16;
    return ua | (ub << 16);
}
__device__ __forceinline__ unsigned short f2bf1(float a) {
    unsigned int ua = __float_as_uint(a);
    return (unsigned short)((ua + 0x7fffu + ((ua >> 16) & 1u)) >> 16);
}

// ---------------------------------------------------------------------------
// MFMA GEMM: H[n][f] = sum_k In[n][k] * W[k][f] -> packed bf16 [N][128].
// BN=false: X is fp32 [N][128].  BN=true: X is packed bf16 [N][64 uints],
// transformed relu(a[k]*x+c[k]) at staging; a,c computed per-thread from
// stats/gamma/beta (bnfinal kernel folded in here).
// Tile: 64 nodes x 128 feats, 256 threads; LDS Xt[64]+Wt[128] rows (bf16,
// stride 136 = 2-way bank aliasing, free per m136). 52 KB -> 3 blocks/CU.
// ---------------------------------------------------------------------------
template <bool BN>
__global__ __launch_bounds__(256) void gemm_kernel(const void* __restrict__ Xv,
                                                   const float* __restrict__ W,
                                                   const float* __restrict__ stats,
                                                   const float* __restrict__ gamma,
                                                   const float* __restrict__ beta,
                                                   float invN,
                                                   unsigned int* __restrict__ Hb,
                                                   int nNodes) {
    __shared__ unsigned int XtU[64 * LSTR];    // bf16 pairs: Xt[node][k]
    __shared__ unsigned int WtU[128 * LSTR];   // bf16 pairs: Wt[feat][k]

    const int tid = threadIdx.x;
    const int bn0 = blockIdx.x * 64;

    // ---- stage W transposed ----
    {
        int f = tid >> 1;
        int kh = (tid & 1) * 64;
        #pragma unroll
        for (int k8 = 0; k8 < 8; ++k8) {
            int k0 = kh + k8 * 8;
            float v[8];
            #pragma unroll
            for (int i = 0; i < 8; ++i) v[i] = W[(size_t)(k0 + i) * F + f];
            uint4 pk;
            pk.x = f2bf2(v[0], v[1]);
            pk.y = f2bf2(v[2], v[3]);
            pk.z = f2bf2(v[4], v[5]);
            pk.w = f2bf2(v[6], v[7]);
            *(uint4*)&WtU[f * LSTR + k0 / 2] = pk;
        }
    }
    // ---- stage X tile as bf16, optional BN+ReLU (BN coeffs computed here) ----
    {
        const int kq = tid & 31;               // (tid + it*256) & 31 is constant
        float4 a4, c4;
        if (BN) {
            float4 s  = ((const float4*)stats)[kq];
            float4 sq = ((const float4*)(stats + 128))[kq];
            float4 g4 = ((const float4*)gamma)[kq];
            float4 b4 = ((const float4*)beta)[kq];
            float m;
            m = s.x * invN; a4.x = g4.x * rsqrtf(sq.x * invN - m * m + 1e-5f); c4.x = b4.x - m * a4.x;
            m = s.y * invN; a4.y = g4.y * rsqrtf(sq.y * invN - m * m + 1e-5f); c4.y = b4.y - m * a4.y;
            m = s.z * invN; a4.z = g4.z * rsqrtf(sq.z * invN - m * m + 1e-5f); c4.z = b4.z - m * a4.z;
            m = s.w * invN; a4.w = g4.w * rsqrtf(sq.w * invN - m * m + 1e-5f); c4.w = b4.w - m * a4.w;
        }
        #pragma unroll
        for (int it = 0; it < 8; ++it) {
            int i = tid + it * 256;            // 0..2047
            int n = i >> 5;                    // node 0..63
            int node = bn0 + n;
            uint2 pk = make_uint2(0u, 0u);
            if (BN) {
                uint2 raw = make_uint2(0u, 0u);
                if (node < nNodes) raw = ((const uint2*)Xv)[(size_t)node * 32 + kq];
                float4 v;
                v.x = __uint_as_float(raw.x << 16);
                v.y = __uint_as_float(raw.x & 0xffff0000u);
                v.z = __uint_as_float(raw.y << 16);
                v.w = __uint_as_float(raw.y & 0xffff0000u);
                v.x = fmaxf(fmaf(a4.x, v.x, c4.x), 0.f);
                v.y = fmaxf(fmaf(a4.y, v.y, c4.y), 0.f);
                v.z = fmaxf(fmaf(a4.z, v.z, c4.z), 0.f);
                v.w = fmaxf(fmaf(a4.w, v.w, c4.w), 0.f);
                pk = make_uint2(f2bf2(v.x, v.y), f2bf2(v.z, v.w));
            } else {
                float4 v = make_float4(0.f, 0.f, 0.f, 0.f);
                if (node < nNodes) v = ((const float4*)Xv)[(size_t)node * FQ + kq];
                pk = make_uint2(f2bf2(v.x, v.y), f2bf2(v.z, v.w));
            }
            *(uint2*)&XtU[n * LSTR + kq * 2] = pk;
        }
    }
    __syncthreads();

    // ---- MFMA compute ----
    const int l = tid & 63;
    const int wv = tid >> 6;
    const int quad = l >> 4, lo = l & 15;
    const int fb = wv * 32;

    f32x4 acc[4][2];
    #pragma unroll
    for (int nt = 0; nt < 4; ++nt)
        #pragma unroll
        for (int ft = 0; ft < 2; ++ft) acc[nt][ft] = (f32x4){0.f, 0.f, 0.f, 0.f};

    #pragma unroll
    for (int kc = 0; kc < 4; ++kc) {
        int koff = kc * 16 + quad * 4;
        short8 a[4], b[2];
        #pragma unroll
        for (int nt = 0; nt < 4; ++nt)
            a[nt] = *(const short8*)&XtU[(nt * 16 + lo) * LSTR + koff];
        #pragma unroll
        for (int ft = 0; ft < 2; ++ft)
            b[ft] = *(const short8*)&WtU[(fb + ft * 16 + lo) * LSTR + koff];
        #pragma unroll
        for (int nt = 0; nt < 4; ++nt)
            #pragma unroll
            for (int ft = 0; ft < 2; ++ft)
                acc[nt][ft] = __builtin_amdgcn_mfma_f32_16x16x32_bf16(
                    a[nt], b[ft], acc[nt][ft], 0, 0, 0);
    }

    // ---- epilogue: bf16 store (D: col=lane&15, row=quad*4+reg) ----
    unsigned short* Hs = (unsigned short*)Hb;
    #pragma unroll
    for (int nt = 0; nt < 4; ++nt) {
        #pragma unroll
        for (int reg = 0; reg < 4; ++reg) {
            int node = bn0 + nt * 16 + quad * 4 + reg;
            if (node < nNodes) {
                #pragma unroll
                for (int ft = 0; ft < 2; ++ft)
                    Hs[(size_t)node * F + fb + ft * 16 + lo] = f2bf1(acc[nt][ft][reg]);
            }
        }
    }
}

// ---------------------------------------------------------------------------
// CSR build via deterministic bucket sort — NO returning global atomics.
// ---------------------------------------------------------------------------
__global__ __launch_bounds__(256) void histo_kernel(const int* __restrict__ row,
                                                    int* __restrict__ hist,
                                                    int NB, int E) {
    __shared__ int h[1024];
    int t = threadIdx.x;
    for (int i = t; i < NB; i += 256) h[i] = 0;
    __syncthreads();
    int base = blockIdx.x * TILE + t * 8;
    if (base + 7 < E) {
        int4 a = ((const int4*)row)[(base >> 2) + 0];
        int4 b = ((const int4*)row)[(base >> 2) + 1];
        atomicAdd(&h[a.x >> BSH], 1); atomicAdd(&h[a.y >> BSH], 1);
        atomicAdd(&h[a.z >> BSH], 1); atomicAdd(&h[a.w >> BSH], 1);
        atomicAdd(&h[b.x >> BSH], 1); atomicAdd(&h[b.y >> BSH], 1);
        atomicAdd(&h[b.z >> BSH], 1); atomicAdd(&h[b.w >> BSH], 1);
    } else {
        for (int j = 0; j < 8; ++j)
            if (base + j < E) atomicAdd(&h[row[base + j] >> BSH], 1);
    }
    __syncthreads();
    for (int i = t; i < NB; i += 256) hist[(size_t)blockIdx.x * NB + i] = h[i];
}

__global__ __launch_bounds__(256) void btot_kernel(const int* __restrict__ hist,
                                                   int* __restrict__ total,
                                                   int nT, int NB) {
    int b = blockIdx.x;
    int s = 0;
    for (int t = threadIdx.x; t < nT; t += 256) s += hist[(size_t)t * NB + b];
    __shared__ int red[256];
    red[threadIdx.x] = s;
    __syncthreads();
    for (int o = 128; o > 0; o >>= 1) {
        if (threadIdx.x < o) red[threadIdx.x] += red[threadIdx.x + o];
        __syncthreads();
    }
    if (threadIdx.x == 0) total[b] = red[0];
}

__global__ __launch_bounds__(1024) void bstart_kernel(const int* __restrict__ total,
                                                      int* __restrict__ start,
                                                      int NB, int E) {
    __shared__ int sh[1024];
    int t = threadIdx.x;
    int v = (t < NB) ? total[t] : 0;
    sh[t] = v;
    __syncthreads();
    #pragma unroll
    for (int o = 1; o < 1024; o <<= 1) {
        int add = (t >= o) ? sh[t - o] : 0;
        __syncthreads();
        sh[t] += add;
        __syncthreads();
    }
    if (t < NB) start[t] = sh[t] - v;
    if (t == 0) start[NB] = E;
}

__global__ __launch_bounds__(1024) void boff_kernel(const int* __restrict__ hist,
                                                    const int* __restrict__ start,
                                                    int* __restrict__ off,
                                                    int nT, int NB) {
    __shared__ int sh[1024];
    int b = blockIdx.x, t = threadIdx.x;
    int v = (t < nT) ? hist[(size_t)t * NB + b] : 0;
    sh[t] = v;
    __syncthreads();
    #pragma unroll
    for (int o = 1; o < 1024; o <<= 1) {
        int add = (t >= o) ? sh[t - o] : 0;
        __syncthreads();
        sh[t] += add;
        __syncthreads();
    }
    if (t < nT) off[(size_t)b * nT + t] = start[b] + sh[t] - v;
}

__global__ __launch_bounds__(256) void bplace_kernel(const int* __restrict__ row,
                                                     const int* __restrict__ col,
                                                     const float* __restrict__ w,
                                                     const int* __restrict__ off,
                                                     int2* __restrict__ tmp,
                                                     int nT, int NB, int E) {
    __shared__ int h[1024];
    int t = threadIdx.x, tile = blockIdx.x;
    for (int i = t; i < NB; i += 256) h[i] = 0;
    __syncthreads();
    int base = tile * TILE + t * 8;
    int r[8], c[8];
    float ww[8];
    int nv = 0;
    if (base + 7 < E) {
        int4 ra = ((const int4*)row)[(base >> 2) + 0];
        int4 rb = ((const int4*)row)[(base >> 2) + 1];
        int4 ca = ((const int4*)col)[(base >> 2) + 0];
        int4 cb = ((const int4*)col)[(base >> 2) + 1];
        float4 wa = ((const float4*)w)[(base >> 2) + 0];
        float4 wb = ((const float4*)w)[(base >> 2) + 1];
        r[0] = ra.x; r[1] = ra.y; r[2] = ra.z; r[3] = ra.w;
        r[4] = rb.x; r[5] = rb.y; r[6] = rb.z; r[7] = rb.w;
        c[0] = ca.x; c[1] = ca.y; c[2] = ca.z; c[3] = ca.w;
        c[4] = cb.x; c[5] = cb.y; c[6] = cb.z; c[7] = cb.w;
        ww[0] = wa.x; ww[1] = wa.y; ww[2] = wa.z; ww[3] = wa.w;
        ww[4] = wb.x; ww[5] = wb.y; ww[6] = wb.z; ww[7] = wb.w;
        nv = 8;
    } else {
        for (int j = 0; j < 8; ++j)
            if (base + j < E) { r[nv] = row[base + j]; c[nv] = col[base + j];
                                ww[nv] = w[base + j]; ++nv; }
    }
    #pragma unroll 8
    for (int j = 0; j < 8; ++j) {
        if (j >= nv) break;
        int b = r[j] >> BSH;
        int rank = atomicAdd(&h[b], 1);
        int pos = off[(size_t)b * nT + tile] + rank;
        tmp[pos] = make_int2(((r[j] & (RPB - 1)) << 25) | c[j], __float_as_int(ww[j]));
    }
}

__global__ __launch_bounds__(256) void bsort_kernel(const int2* __restrict__ tmp,
                                                    const int* __restrict__ start,
                                                    int2* __restrict__ pairs,
                                                    int* __restrict__ rowptr,
                                                    int N, int NB, int E) {
    __shared__ int cntB[RPB];
    __shared__ int cntS[RPB];
    __shared__ int sc[RPB];
    __shared__ int2 outP[SCAP];
    int b = blockIdx.x, t = threadIdx.x;
    int s0 = start[b], s1 = start[b + 1];
    int len = s1 - s0;
    if (len > SCAP) len = SCAP;

    if (t < RPB) cntB[t] = 0;
    __syncthreads();

    int2 p[16];
    int np = 0;
    #pragma unroll
    for (int k = 0; k < 16; ++k) {
        int i = t + k * 256;
        if (i < len) { p[k] = tmp[s0 + i]; ++np; }
    }
    #pragma unroll
    for (int k = 0; k < 16; ++k) {
        if (k >= np) break;
        atomicAdd(&cntB[((unsigned)p[k].x) >> 25], 1);
    }
    __syncthreads();
    int val = (t < RPB) ? cntB[t] : 0;
    if (t < RPB) sc[t] = val;
    __syncthreads();
    #pragma unroll
    for (int o = 1; o < RPB; o <<= 1) {
        int add = (t < RPB && t >= o) ? sc[t - o] : 0;
        __syncthreads();
        if (t < RPB) sc[t] += add;
        __syncthreads();
    }
    if (t < RPB) { int ex = sc[t] - val; cntB[t] = ex; cntS[t] = ex; }
    __syncthreads();
    #pragma unroll
    for (int k = 0; k < 16; ++k) {
        if (k >= np) break;
        int rl = ((unsigned)p[k].x) >> 25;
        int lr = atomicAdd(&cntB[rl], 1);
        outP[lr] = make_int2(p[k].x & 0x1ffffff, p[k].y);
    }
    __syncthreads();
    for (int i = t; i < len; i += 256) pairs[s0 + i] = outP[i];
    int r0 = b * RPB;
    if (t < RPB && r0 + t < N) rowptr[r0 + t] = s0 + cntS[t];
    if (b == NB - 1 && t == 0) rowptr[N] = E;
}

// ---------------------------------------------------------------------------
// CSR SpMM, bf16 gather, 16-B/lane: one wave per row; lane groups of 16 handle
// 4 edges concurrently (uint4 = 8 feats per lane); shfl_xor reduction at end.
// 256-B contiguous gathers per edge (16 lanes) — the proven-fast granule.
// v5 delta vs round-0: outputs are NON-TEMPORAL stores so the 12.8/51 MB
// streaming writes don't evict the gather-hot H from L2/L3.
// BF16OUT: packs result to bf16 (layer 1); else fp32 (final output).
// ---------------------------------------------------------------------------
template <bool BF16OUT>
__global__ __launch_bounds__(256) void spmm_csr_kernel(const int* __restrict__ rowptr,
                                                       const int2* __restrict__ pairs,
                                                       const unsigned int* __restrict__ Hb,
                                                       const float* __restrict__ bias,
                                                       void* __restrict__ outv, int N) {
    int r = blockIdx.x * 4 + (threadIdx.x >> 6);
    if (r >= N) return;
    const int l = threadIdx.x & 63;
    const int g = l >> 4, q = l & 15;          // edge subgroup, 8-feat chunk
    const uint4* H4 = (const uint4*)Hb;        // row = 16 uint4

    float acc[8];
    #pragma unroll
    for (int j = 0; j < 8; ++j) acc[j] = 0.f;

    int i = rowptr[r], end = rowptr[r + 1];

    for (; i + 16 <= end; i += 16) {
        int2 p[4];
        uint4 gv[4];
        #pragma unroll
        for (int k = 0; k < 4; ++k) p[k] = pairs[i + 4 * k + g];
        #pragma unroll
        for (int k = 0; k < 4; ++k) gv[k] = H4[(size_t)p[k].x * 16 + q];
        #pragma unroll
        for (int k = 0; k < 4; ++k) {
            float wt = __int_as_float(p[k].y);
            unsigned int uu[4] = {gv[k].x, gv[k].y, gv[k].z, gv[k].w};
            #pragma unroll
            for (int j = 0; j < 4; ++j) {
                acc[2 * j]     = fmaf(wt, __uint_as_float(uu[j] << 16), acc[2 * j]);
                acc[2 * j + 1] = fmaf(wt, __uint_as_float(uu[j] & 0xffff0000u), acc[2 * j + 1]);
            }
        }
    }
    for (; i + 4 <= end; i += 4) {
        int2 p = pairs[i + g];
        uint4 gv = H4[(size_t)p.x * 16 + q];
        float wt = __int_as_float(p.y);
        unsigned int uu[4] = {gv.x, gv.y, gv.z, gv.w};
        #pragma unroll
        for (int j = 0; j < 4; ++j) {
            acc[2 * j]     = fmaf(wt, __uint_as_float(uu[j] << 16), acc[2 * j]);
            acc[2 * j + 1] = fmaf(wt, __uint_as_float(uu[j] & 0xffff0000u), acc[2 * j + 1]);
        }
    }
    if (i < end) {
        int e = i + g;
        int2 p = (e < end) ? pairs[e] : make_int2(0, 0);   // wt=0 for pad lanes
        uint4 gv = H4[(size_t)p.x * 16 + q];
        float wt = __int_as_float(p.y);
        unsigned int uu[4] = {gv.x, gv.y, gv.z, gv.w};
        #pragma unroll
        for (int j = 0; j < 4; ++j) {
            acc[2 * j]     = fmaf(wt, __uint_as_float(uu[j] << 16), acc[2 * j]);
            acc[2 * j + 1] = fmaf(wt, __uint_as_float(uu[j] & 0xffff0000u), acc[2 * j + 1]);
        }
    }

    // reduce the 4 edge-subgroups (lanes q, q+16, q+32, q+48)
    #pragma unroll
    for (int j = 0; j < 8; ++j) {
        acc[j] += __shfl_xor(acc[j], 16, 64);
        acc[j] += __shfl_xor(acc[j], 32, 64);
    }

    if (g == 0) {
        if (bias) {
            float4 b0 = ((const float4*)bias)[q * 2];
            float4 b1 = ((const float4*)bias)[q * 2 + 1];
            acc[0] += b0.x; acc[1] += b0.y; acc[2] += b0.z; acc[3] += b0.w;
            acc[4] += b1.x; acc[5] += b1.y; acc[6] += b1.z; acc[7] += b1.w;
        }
        if (BF16OUT) {
            u32x4 pk;
            pk.x = f2bf2(acc[0], acc[1]);
            pk.y = f2bf2(acc[2], acc[3]);
            pk.z = f2bf2(acc[4], acc[5]);
            pk.w = f2bf2(acc[6], acc[7]);
            __builtin_nontemporal_store(pk, &((u32x4*)outv)[(size_t)r * 16 + q]);
        } else {
            f32x4 v0 = (f32x4){acc[0], acc[1], acc[2], acc[3]};
            f32x4 v1 = (f32x4){acc[4], acc[5], acc[6], acc[7]};
            f32x4* O = (f32x4*)outv;
            __builtin_nontemporal_store(v0, &O[(size_t)r * 32 + q * 2]);
            __builtin_nontemporal_store(v1, &O[(size_t)r * 32 + q * 2 + 1]);
        }
    }
}

// ---------------------------------------------------------------------------
// BN batch statistics over packed-bf16 input: per-feature sum and sumsq.
// ---------------------------------------------------------------------------
__global__ __launch_bounds__(256) void bnstats_kernel(const unsigned int* __restrict__ Hu,
                                                      float* __restrict__ sums,
                                                      int nNodes) {
    int u = threadIdx.x & 63;   // uint index: feats 2u, 2u+1
    int g = threadIdx.x >> 6;   // 0..3
    int stride = gridDim.x * 4;
    float s0 = 0.f, s1 = 0.f, q0 = 0.f, q1 = 0.f;
    for (int n = blockIdx.x * 4 + g; n < nNodes; n += stride) {
        unsigned int v = Hu[(size_t)n * FU + u];
        float a = __uint_as_float(v << 16);
        float b = __uint_as_float(v & 0xffff0000u);
        s0 += a; s1 += b;
        q0 = fmaf(a, a, q0); q1 = fmaf(b, b, q1);
    }
    __shared__ float4 red[256];
    red[threadIdx.x] = make_float4(s0, s1, q0, q1);
    __syncthreads();
    if (g == 0) {
        float4 r0 = red[u], r1 = red[64 + u], r2 = red[128 + u], r3 = red[192 + u];
        atomicAdd(&sums[2 * u],           r0.x + r1.x + r2.x + r3.x);
        atomicAdd(&sums[2 * u + 1],       r0.y + r1.y + r2.y + r3.y);
        atomicAdd(&sums[128 + 2 * u],     r0.z + r1.z + r2.z + r3.z);
        atomicAdd(&sums[128 + 2 * u + 1], r0.w + r1.w + r2.w + r3.w);
    }
}

extern "C" void kernel_launch(void* const* d_in, const int* in_sizes, int n_in,
                              void* d_out, int out_size, void* d_ws, size_t ws_size,
                              hipStream_t stream) {
    const float* x    = (const float*)d_in[0];
    const int*   erow = (const int*)d_in[1];
    const int*   ecol = (const int*)d_in[2];
    const float* ew   = (const float*)d_in[3];
    const float* W1   = (const float*)d_in[4];
    // d_in[5] = b1: unused — cancels exactly under BatchNorm mean subtraction.
    const float* W2   = (const float*)d_in[6];
    const float* b2   = (const float*)d_in[7];
    const float* gmm  = (const float*)d_in[8];
    const float* beta = (const float*)d_in[9];
    float* out = (float*)d_out;

    const int N = in_sizes[0] / F;   // 100000
    const int E = in_sizes[1];       // 1600000

    const int NB = (N + RPB - 1) / RPB;     // 782
    const int nT = (E + TILE - 1) / TILE;   // 782

    // ---- workspace carve-up ----
    unsigned int* buf1   = (unsigned int*)d_ws;                   // N*FU bf16 (h1)
    unsigned int* Hb     = buf1 + (size_t)N * FU;                 // N*FU bf16 (h0/h2)
    float*        stats  = (float*)(Hb + (size_t)N * FU);         // 256
    int*          rowptr = (int*)(stats + 256);                   // N+2
    int*          start  = rowptr + N + 2;                        // 1028
    int*          total  = start + 1028;                          // 1024
    int*          hist   = total + 1024;                          // nT*NB
    int*          off    = hist + (size_t)nT * NB;                // NB*nT
    int2*         tmp    = (int2*)(off + (size_t)NB * nT);        // E
    int2*         pairs  = tmp + E;                               // E

    const int gemmGrid = (N + 63) / 64;
    const int spmmGrid = (N + 3) / 4;

    hipMemsetAsync(stats, 0, 256 * sizeof(float), stream);

    // ---- build CSR: deterministic bucket sort, shared by both layers ----
    histo_kernel<<<nT, 256, 0, stream>>>(erow, hist, NB, E);
    btot_kernel<<<NB, 256, 0, stream>>>(hist, total, nT, NB);
    bstart_kernel<<<1, 1024, 0, stream>>>(total, start, NB, E);
    boff_kernel<<<NB, 1024, 0, stream>>>(hist, start, off, nT, NB);
    bplace_kernel<<<nT, 256, 0, stream>>>(erow, ecol, ew, off, tmp, nT, NB, E);
    bsort_kernel<<<NB, 256, 0, stream>>>(tmp, start, pairs, rowptr, N, NB, E);

    // Layer 1: Hb = bf16(x @ W1) ; buf1 = bf16(A @ Hb)
    gemm_kernel<false><<<gemmGrid, 256, 0, stream>>>(x, W1, nullptr, nullptr,
                                                     nullptr, 0.f, Hb, N);
    spmm_csr_kernel<true><<<spmmGrid, 256, 0, stream>>>(rowptr, pairs, Hb,
                                                        nullptr, buf1, N);
    // BN stats (BN-fold happens inside gemm<true>)
    bnstats_kernel<<<400, 256, 0, stream>>>(buf1, stats, N);
    // Layer 2: Hb = bf16(relu(bn(buf1)) @ W2) ; out = A @ Hb + b2 (fp32)
    gemm_kernel<true><<<gemmGrid, 256, 0, stream>>>(buf1, W2, stats, gmm, beta,
                                                    1.0f / (float)N, Hb, N);
    spmm_csr_kernel<false><<<spmmGrid, 256, 0, stream>>>(rowptr, pairs, Hb,
                                                         b2, out, N);
}